// Round 1
// baseline (1851.678 us; speedup 1.0000x reference)
//
#include <hip/hip_runtime.h>
#include <cfloat>

// Problem constants (from reference)
#define NROWS   32768      // 8*4096 z vectors
#define NCODES  8192
#define KDIM    256
#define QOUT_OFFSET (NROWS * KDIM)   // index region start in d_out (floats)

// Tiling
#define BM 128   // rows per block
#define BN 128   // codes per tile step
#define BK 32    // k chunk
#define LDT 132  // LDS leading dim (BM/BN + 4 pad, keeps float4 alignment)

// ---------------------------------------------------------------------------
// Kernel 1: cnorm[m] = ||codebook[m]||^2.  One wave per code row.
// ---------------------------------------------------------------------------
__global__ void vq_cnorm_kernel(const float* __restrict__ cb,
                                float* __restrict__ cnorm) {
    int gid  = blockIdx.x * blockDim.x + threadIdx.x;
    int code = gid >> 6;          // wave index = code row
    int lane = threadIdx.x & 63;
    if (code >= NCODES) return;
    float4 v = ((const float4*)cb)[code * (KDIM / 4) + lane];
    float s = v.x * v.x + v.y * v.y + v.z * v.z + v.w * v.w;
    #pragma unroll
    for (int off = 32; off >= 1; off >>= 1)
        s += __shfl_down(s, off, 64);
    if (lane == 0) cnorm[code] = s;
}

// ---------------------------------------------------------------------------
// Kernel 2: fused distance GEMM + argmin + gather.
// Block: 512 threads (8 waves). Each block owns BM=128 rows, scans all codes.
// ---------------------------------------------------------------------------
__global__ __launch_bounds__(512) void vq_main_kernel(
        const float* __restrict__ z, const float* __restrict__ cb,
        const float* __restrict__ cnorm, float* __restrict__ quant,
        float* __restrict__ idx_out) {

    __shared__ float As[BK][LDT];   // z tile, transposed: As[k][row]
    __shared__ float Bs[BK][LDT];   // code tile, transposed: Bs[k][code]
    __shared__ int   bestIdx[BM];

    const int t    = threadIdx.x;
    const int tj   = t & 31;        // code quad: covers 128 codes
    const int tr   = t >> 5;        // row octet: 16 * 8 = 128 rows
    const int row0 = blockIdx.x * BM;

    // staging mapping: 4k x 2row micro-transpose per thread
    const int kq  = t & 7;          // k quad (8*4 = 32 k)
    const int rb2 = t >> 3;         // pair index (64 pairs -> 128 rows/codes)

    float acc[8][4];
    float minv[8];
    int   mini[8];
    #pragma unroll
    for (int r = 0; r < 8; ++r) {
        minv[r] = FLT_MAX; mini[r] = 0;
        #pragma unroll
        for (int c = 0; c < 4; ++c) acc[r][c] = 0.f;
    }

    const float4* z4  = (const float4*)z;
    const float4* cb4 = (const float4*)cb;

    for (int ct = 0; ct < NCODES / BN; ++ct) {
        for (int kc = 0; kc < KDIM / BK; ++kc) {
            __syncthreads();
            // ---- stage A (z rows) ----
            {
                int r0 = rb2 * 2;
                float4 L0 = z4[(size_t)(row0 + r0)     * (KDIM / 4) + kc * (BK / 4) + kq];
                float4 L1 = z4[(size_t)(row0 + r0 + 1) * (KDIM / 4) + kc * (BK / 4) + kq];
                ((float2*)&As[kq * 4 + 0][r0])[0] = make_float2(L0.x, L1.x);
                ((float2*)&As[kq * 4 + 1][r0])[0] = make_float2(L0.y, L1.y);
                ((float2*)&As[kq * 4 + 2][r0])[0] = make_float2(L0.z, L1.z);
                ((float2*)&As[kq * 4 + 3][r0])[0] = make_float2(L0.w, L1.w);
            }
            // ---- stage B (codebook rows) ----
            {
                int c0 = rb2 * 2;
                float4 L0 = cb4[(size_t)(ct * BN + c0)     * (KDIM / 4) + kc * (BK / 4) + kq];
                float4 L1 = cb4[(size_t)(ct * BN + c0 + 1) * (KDIM / 4) + kc * (BK / 4) + kq];
                ((float2*)&Bs[kq * 4 + 0][c0])[0] = make_float2(L0.x, L1.x);
                ((float2*)&Bs[kq * 4 + 1][c0])[0] = make_float2(L0.y, L1.y);
                ((float2*)&Bs[kq * 4 + 2][c0])[0] = make_float2(L0.z, L1.z);
                ((float2*)&Bs[kq * 4 + 3][c0])[0] = make_float2(L0.w, L1.w);
            }
            __syncthreads();

            // ---- compute: 8x4 outer product per thread ----
            #pragma unroll
            for (int k = 0; k < BK; ++k) {
                float4 a0 = *(const float4*)&As[k][tr * 8];
                float4 a1 = *(const float4*)&As[k][tr * 8 + 4];
                float4 b  = *(const float4*)&Bs[k][tj * 4];
                float av[8] = {a0.x, a0.y, a0.z, a0.w, a1.x, a1.y, a1.z, a1.w};
                float bv[4] = {b.x, b.y, b.z, b.w};
                #pragma unroll
                for (int r = 0; r < 8; ++r)
                    #pragma unroll
                    for (int c = 0; c < 4; ++c)
                        acc[r][c] = fmaf(av[r], bv[c], acc[r][c]);
            }
        }

        // ---- epilogue for this code tile: dist = ||c||^2 - 2 z.c ----
        #pragma unroll
        for (int c = 0; c < 4; ++c) {
            int code = ct * BN + tj * 4 + c;
            float cn = cnorm[code];
            #pragma unroll
            for (int r = 0; r < 8; ++r) {
                float d = fmaf(-2.f, acc[r][c], cn);
                if (d < minv[r]) { minv[r] = d; mini[r] = code; }  // codes ascend -> first-min kept
                acc[r][c] = 0.f;
            }
        }
    }

    // ---- cross-thread argmin reduction (32 code-threads per row) ----
    __syncthreads();
    float* rv = &As[0][0];      // 128*32 floats fits in As
    int*   ri = (int*)&Bs[0][0];
    #pragma unroll
    for (int r = 0; r < 8; ++r) {
        rv[(tr * 8 + r) * 32 + tj] = minv[r];
        ri[(tr * 8 + r) * 32 + tj] = mini[r];
    }
    __syncthreads();
    if (t < BM) {
        float bv = rv[t * 32];
        int   bi = ri[t * 32];
        for (int j = 1; j < 32; ++j) {
            float v = rv[t * 32 + j];
            int   id = ri[t * 32 + j];
            if (v < bv || (v == bv && id < bi)) { bv = v; bi = id; }
        }
        bestIdx[t] = bi;
        idx_out[row0 + t] = (float)bi;   // index as float (d_out is fp32 flat)
    }
    __syncthreads();

    // ---- gather codebook rows into quantized output (bit-exact fp32) ----
    {
        int row = t >> 2, seg = t & 3;
        int best = bestIdx[row];
        const float4* src = &cb4[(size_t)best * (KDIM / 4)];
        float4* dst = (float4*)quant + (size_t)(row0 + row) * (KDIM / 4);
        #pragma unroll
        for (int i = 0; i < 16; ++i)
            dst[seg * 16 + i] = src[seg * 16 + i];
    }
}

// ---------------------------------------------------------------------------
extern "C" void kernel_launch(void* const* d_in, const int* in_sizes, int n_in,
                              void* d_out, int out_size, void* d_ws, size_t ws_size,
                              hipStream_t stream) {
    const float* z  = (const float*)d_in[0];
    const float* cb = (const float*)d_in[1];
    float* quant   = (float*)d_out;
    float* idx_out = (float*)d_out + QOUT_OFFSET;
    float* cnorm   = (float*)d_ws;            // 8192 floats

    vq_cnorm_kernel<<<NCODES / 4, 256, 0, stream>>>(cb, cnorm);
    vq_main_kernel<<<NROWS / BM, 512, 0, stream>>>(z, cb, cnorm, quant, idx_out);
}